// Round 13
// baseline (423.823 us; speedup 1.0000x reference)
//
#include <hip/hip_runtime.h>

// Max-unpooling scatter-add, hist-free radix (2048 buckets): LDS batch-sort
// + global atomic cursor allocation, then merged accumulate (pairs in regs,
// 2 x 128 KB LDS sweeps).
//   out = zeros(total); out[ind[i]] += x[i]
// N = 2^25 pairs, OUT = 2^27 floats (536.9 MB).
//
// R13: intermediate shrunk to val(f32)+loc(u16) split arrays, CSH=16 so the
// 16-bit local offset is exact. Total intermediate = 214 MB < 256 MB L3 ->
// written cacheable, re-read from L3, never round-trips HBM. ind/x reads and
// out writes are non-temporal so they don't evict it.

typedef float    f32x4 __attribute__((ext_vector_type(4)));
typedef int      i32x4 __attribute__((ext_vector_type(4)));
typedef unsigned u32x2 __attribute__((ext_vector_type(2)));

#define N_TOT   (1 << 25)     // input pairs
#define OUT_TOT (1 << 27)     // output floats
#define T1      1024          // scatter tiles
#define PT      (N_TOT / T1)  // 32768 pairs/tile
#define PT4     (PT / 4)      // 8192 vec4/tile
#define NB1     2048          // buckets
#define CSH     16            // bucket = idx >> 16 (window 2^16 floats = 256 KB)
#define CAP     17408         // per-bucket capacity (mean 16384 + 8 sigma)
#define NSUB    2             // sweeps: bit 15 of loc16
#define WFL     32768         // floats per sweep window (128 KB LDS)
#define BATCH   16384         // pairs per sort batch (128 KB LDS sbuf)
#define KREG    34            // pairs/thread in k_waccum (512 thr: CAP exactly)

// ---- K1: scatter with LDS batch-sort + atomic segment allocation ----
__global__ __launch_bounds__(1024) void k_scatter(const float* __restrict__ x,
                                                  const int* __restrict__ ind,
                                                  unsigned* __restrict__ gcur,
                                                  float* __restrict__ P1v,
                                                  unsigned short* __restrict__ P1l) {
  __shared__ u32x2    sbuf[BATCH];                        // 128 KB
  __shared__ unsigned hist[NB1], sbase[NB1], alloc[NB1];  // 24 KB (total 152 KB)
  const int t = blockIdx.x;
  const i32x4* pi = reinterpret_cast<const i32x4*>(ind) + (size_t)t * PT4;
  const f32x4* pv = reinterpret_cast<const f32x4*>(x)  + (size_t)t * PT4;

  for (int bt = 0; bt < 2; ++bt) {
    const int v0 = bt * (BATCH / 4);
    i32x4 idx[4];
    f32x4 val[4];
    #pragma unroll
    for (int q = 0; q < 4; ++q) {
      idx[q] = __builtin_nontemporal_load(pi + v0 + q * 1024 + threadIdx.x);
      val[q] = __builtin_nontemporal_load(pv + v0 + q * 1024 + threadIdx.x);
    }
    hist[threadIdx.x] = 0;
    hist[threadIdx.x + 1024] = 0;
    __syncthreads();
    unsigned r[16];
    #pragma unroll
    for (int q = 0; q < 4; ++q) {
      r[4 * q + 0] = atomicAdd(&hist[(unsigned)idx[q].x >> CSH], 1u);
      r[4 * q + 1] = atomicAdd(&hist[(unsigned)idx[q].y >> CSH], 1u);
      r[4 * q + 2] = atomicAdd(&hist[(unsigned)idx[q].z >> CSH], 1u);
      r[4 * q + 3] = atomicAdd(&hist[(unsigned)idx[q].w >> CSH], 1u);
    }
    __syncthreads();
    // Allocate per-bucket segments: 1 global atomic/bucket on 2048 hot
    // (L2-resident) addresses; latency hides under the scan below.
    alloc[threadIdx.x] = atomicAdd(&gcur[threadIdx.x], hist[threadIdx.x]);
    alloc[threadIdx.x + 1024] =
        atomicAdd(&gcur[threadIdx.x + 1024], hist[threadIdx.x + 1024]);
    if (threadIdx.x < 64) {   // exclusive scan of hist[2048]: 32 entries/lane
      const unsigned lane = threadIdx.x;
      unsigned h[32], sum = 0;
      #pragma unroll
      for (int j = 0; j < 32; ++j) { h[j] = hist[32 * lane + j]; sum += h[j]; }
      unsigned inc = sum;
      for (int off = 1; off < 64; off <<= 1) {
        unsigned o = __shfl_up(inc, off, 64);
        if (lane >= (unsigned)off) inc += o;
      }
      unsigned exc = inc - sum;
      #pragma unroll
      for (int j = 0; j < 32; ++j) { sbase[32 * lane + j] = exc; exc += h[j]; }
    }
    __syncthreads();
    #pragma unroll
    for (int q = 0; q < 4; ++q) {
      sbuf[sbase[(unsigned)idx[q].x >> CSH] + r[4 * q + 0]] =
          (u32x2){__float_as_uint(val[q].x), (unsigned)idx[q].x};
      sbuf[sbase[(unsigned)idx[q].y >> CSH] + r[4 * q + 1]] =
          (u32x2){__float_as_uint(val[q].y), (unsigned)idx[q].y};
      sbuf[sbase[(unsigned)idx[q].z >> CSH] + r[4 * q + 2]] =
          (u32x2){__float_as_uint(val[q].z), (unsigned)idx[q].z};
      sbuf[sbase[(unsigned)idx[q].w >> CSH] + r[4 * q + 3]] =
          (u32x2){__float_as_uint(val[q].w), (unsigned)idx[q].w};
    }
    __syncthreads();
    #pragma unroll
    for (int k = 0; k < BATCH / 1024; ++k) {   // 16 coalesced segment stores
      unsigned j = (unsigned)(k * 1024 + threadIdx.x);
      u32x2 q = sbuf[j];
      unsigned b = q.y >> CSH;
      unsigned pos = alloc[b] + (j - sbase[b]);
      if (pos < CAP) {   // statistically impossible overflow; guard anyway
        // CACHEABLE stores: intermediate (214 MB) must stay L3-resident.
        P1v[(size_t)b * CAP + pos] = __uint_as_float(q.x);
        P1l[(size_t)b * CAP + pos] = (unsigned short)(q.y & 0xFFFFu);
      }
    }
    __syncthreads();
  }
}

// ---- K2: merged accumulate. Pairs in regs (no spill), 2 x 128 KB sweeps ----
__global__ __launch_bounds__(512, 2) void k_waccum(const float* __restrict__ P1v,
                                                   const unsigned short* __restrict__ P1l,
                                                   const unsigned* __restrict__ gcur,
                                                   float* __restrict__ out) {
  __shared__ float w[WFL];   // 128 KB
  const int c = blockIdx.x;
  const unsigned len = min(gcur[c], (unsigned)CAP);
  const float* Pv = P1v + (size_t)c * CAP;
  const unsigned short* Pl = P1l + (size_t)c * CAP;
  float    pv[KREG];   // 34 VGPR
  unsigned pl[KREG];   // 34 VGPR
  #pragma unroll
  for (int k = 0; k < KREG; ++k) {
    unsigned j = (unsigned)(k * 512) + threadIdx.x;
    if (j < len) {
      pv[k] = Pv[j];               // L3-resident read
      pl[k] = (unsigned)Pl[j];
    } else {
      pv[k] = 0.0f;                // sentinel: adds 0.0 at slot 0, harmless
      pl[k] = 0u;
    }
  }
  f32x4* w4 = reinterpret_cast<f32x4*>(w);
  for (int sub = 0; sub < NSUB; ++sub) {
    for (int i = threadIdx.x; i < WFL / 4; i += 512) w4[i] = (f32x4){0.f, 0.f, 0.f, 0.f};
    __syncthreads();
    #pragma unroll
    for (int k = 0; k < KREG; ++k) {
      if ((pl[k] >> 15) == (unsigned)sub)
        atomicAdd(&w[pl[k] & (WFL - 1)], pv[k]);   // ds_add_f32
    }
    __syncthreads();
    f32x4* o = reinterpret_cast<f32x4*>(out + ((size_t)c << CSH) + ((size_t)sub << 15));
    for (int i = threadIdx.x; i < WFL / 4; i += 512)
      __builtin_nontemporal_store(w4[i], o + i);
    __syncthreads();
  }
}

// ---- Fallback: plain atomic scatter (measured ~1.77 ms) ----
__global__ __launch_bounds__(256) void unpool_scatter_kernel(
    const float* __restrict__ x, const int* __restrict__ ind,
    float* __restrict__ out, int n4) {
  int i = blockIdx.x * blockDim.x + threadIdx.x;
  if (i >= n4) return;
  f32x4 v  = reinterpret_cast<const f32x4*>(x)[i];
  i32x4 id = reinterpret_cast<const i32x4*>(ind)[i];
  unsafeAtomicAdd(&out[id.x], v.x);
  unsafeAtomicAdd(&out[id.y], v.y);
  unsafeAtomicAdd(&out[id.z], v.z);
  unsafeAtomicAdd(&out[id.w], v.w);
}

extern "C" void kernel_launch(void* const* d_in, const int* in_sizes, int n_in,
                              void* d_out, int out_size, void* d_ws, size_t ws_size,
                              hipStream_t stream) {
  const float* x   = (const float*)d_in[0];
  const int*   ind = (const int*)d_in[1];
  float*       out = (float*)d_out;
  const int n = in_sizes[0];

  // ws layout: gcur[2048] | P1v (142.6 MB) | P1l (71.3 MB)  -> ~214 MB (< L3)
  const size_t szG  = ((size_t)NB1 * sizeof(unsigned) + 255) & ~(size_t)255;
  const size_t szPv = (size_t)NB1 * CAP * sizeof(float);
  const size_t szPl = (size_t)NB1 * CAP * sizeof(unsigned short);
  const size_t need = szG + szPv + szPl;

  const bool shape_ok = (n == N_TOT) && (out_size == OUT_TOT);

  if (!shape_ok || ws_size < need) {
    (void)hipMemsetAsync(d_out, 0, (size_t)out_size * sizeof(float), stream);
    const int n4 = n / 4;
    unpool_scatter_kernel<<<(n4 + 255) / 256, 256, 0, stream>>>(x, ind, out, n4);
    return;
  }

  char* ws = (char*)d_ws;
  unsigned*       gcur = (unsigned*)ws;
  float*          P1v  = (float*)(ws + szG);
  unsigned short* P1l  = (unsigned short*)(ws + szG + szPv);

  (void)hipMemsetAsync(gcur, 0, (size_t)NB1 * sizeof(unsigned), stream);
  k_scatter<<<T1,  1024, 0, stream>>>(x, ind, gcur, P1v, P1l);
  k_waccum <<<NB1,  512, 0, stream>>>(P1v, P1l, gcur, out);
  // Output fully covered by dense windows -> no memset of d_out needed.
}

// Round 14
// 382.467 us; speedup vs baseline: 1.1081x; 1.1081x over previous
//
#include <hip/hip_runtime.h>

// Max-unpooling scatter-add, hist-free radix (1024 buckets): LDS batch-sort
// + global atomic cursor allocation into fixed-capacity bucket regions, then
// merged accumulate with pairs held in registers (512 thr x 72 pairs = 144
// VGPR, no spill), 4 x 128 KB LDS sweeps.
//   out = zeros(total); out[ind[i]] += x[i]
// N = 2^25 pairs, OUT = 2^27 floats (536.9 MB).
//
// R14 = R12 (best, 379 us) + paired 16 B P1 stores/loads: consecutive sorted
// sbuf entries share a bucket 15/16 of the time -> one global_store_dwordx4
// instead of two dwordx2 (halves store instrs + L2 write transactions).
// (R13's 6 B/pair L3-residency split REGRESSED: u16 scattered stores cost
// more than the L3 hit-rate gained. Reverted.)

typedef float    f32x4 __attribute__((ext_vector_type(4)));
typedef int      i32x4 __attribute__((ext_vector_type(4)));
typedef unsigned u32x2 __attribute__((ext_vector_type(2)));
typedef unsigned u32x4 __attribute__((ext_vector_type(4)));

#define N_TOT   (1 << 25)     // input pairs
#define OUT_TOT (1 << 27)     // output floats
#define T1      1024          // scatter tiles
#define PT      (N_TOT / T1)  // 32768 pairs/tile
#define PT4     (PT / 4)      // 8192 vec4/tile
#define NB1     1024          // buckets
#define CSH     17            // bucket = idx >> 17 (window 2^17 floats = 512 KB)
#define CAP     36864         // per-bucket capacity (mean 32768 + 22 sigma), even
#define SSH     15            // sweep = (idx >> 15) & 3
#define NSUB    4
#define WFL     32768         // floats per sweep window (128 KB LDS)
#define BATCH   16384         // pairs per sort batch (128 KB LDS sbuf)
#define KREG    72            // pairs/thread in k_waccum (512 thr: CAP exactly)

// ---- K1: scatter with LDS batch-sort + atomic segment allocation ----
__global__ __launch_bounds__(1024) void k_scatter(const float* __restrict__ x,
                                                  const int* __restrict__ ind,
                                                  unsigned* __restrict__ gcur,
                                                  u32x2* __restrict__ P1) {
  __shared__ u32x2    sbuf[BATCH];                        // 128 KB
  __shared__ unsigned hist[NB1], sbase[NB1], alloc[NB1];  // 12 KB
  const int t = blockIdx.x;
  const i32x4* pi = reinterpret_cast<const i32x4*>(ind) + (size_t)t * PT4;
  const f32x4* pv = reinterpret_cast<const f32x4*>(x)  + (size_t)t * PT4;

  for (int bt = 0; bt < 2; ++bt) {
    const int v0 = bt * (BATCH / 4);
    i32x4 idx[4];
    f32x4 val[4];
    #pragma unroll
    for (int q = 0; q < 4; ++q) {
      idx[q] = __builtin_nontemporal_load(pi + v0 + q * 1024 + threadIdx.x);
      val[q] = __builtin_nontemporal_load(pv + v0 + q * 1024 + threadIdx.x);
    }
    hist[threadIdx.x] = 0;
    __syncthreads();
    unsigned r[16];
    #pragma unroll
    for (int q = 0; q < 4; ++q) {
      r[4 * q + 0] = atomicAdd(&hist[(unsigned)idx[q].x >> CSH], 1u);
      r[4 * q + 1] = atomicAdd(&hist[(unsigned)idx[q].y >> CSH], 1u);
      r[4 * q + 2] = atomicAdd(&hist[(unsigned)idx[q].z >> CSH], 1u);
      r[4 * q + 3] = atomicAdd(&hist[(unsigned)idx[q].w >> CSH], 1u);
    }
    __syncthreads();
    // Allocate this batch's per-bucket segments: 1 global atomic/bucket on
    // 1024 hot (L2-resident) addresses. Latency hides under the scan.
    alloc[threadIdx.x] = atomicAdd(&gcur[threadIdx.x], hist[threadIdx.x]);
    if (threadIdx.x < 64) {   // exclusive scan of hist[1024]: 16 entries/lane
      const unsigned lane = threadIdx.x;
      unsigned h[16], sum = 0;
      #pragma unroll
      for (int j = 0; j < 16; ++j) { h[j] = hist[16 * lane + j]; sum += h[j]; }
      unsigned inc = sum;
      for (int off = 1; off < 64; off <<= 1) {
        unsigned o = __shfl_up(inc, off, 64);
        if (lane >= (unsigned)off) inc += o;
      }
      unsigned exc = inc - sum;
      #pragma unroll
      for (int j = 0; j < 16; ++j) { sbase[16 * lane + j] = exc; exc += h[j]; }
    }
    __syncthreads();
    #pragma unroll
    for (int q = 0; q < 4; ++q) {
      sbuf[sbase[(unsigned)idx[q].x >> CSH] + r[4 * q + 0]] =
          (u32x2){__float_as_uint(val[q].x), (unsigned)idx[q].x};
      sbuf[sbase[(unsigned)idx[q].y >> CSH] + r[4 * q + 1]] =
          (u32x2){__float_as_uint(val[q].y), (unsigned)idx[q].y};
      sbuf[sbase[(unsigned)idx[q].z >> CSH] + r[4 * q + 2]] =
          (u32x2){__float_as_uint(val[q].z), (unsigned)idx[q].z};
      sbuf[sbase[(unsigned)idx[q].w >> CSH] + r[4 * q + 3]] =
          (u32x2){__float_as_uint(val[q].w), (unsigned)idx[q].w};
    }
    __syncthreads();
    // Paired segment stores: consecutive sorted entries share a bucket
    // 15/16 of the time -> 16 B store (dwordx4, dword-aligned OK on CDNA).
    #pragma unroll
    for (int k = 0; k < BATCH / 2048; ++k) {   // 8 paired stores/thread
      unsigned j2 = (unsigned)((k * 1024 + threadIdx.x) * 2);
      u32x2 q0 = sbuf[j2], q1 = sbuf[j2 + 1];
      unsigned b0 = q0.y >> CSH, b1 = q1.y >> CSH;
      unsigned pos0 = alloc[b0] + (j2 - sbase[b0]);
      if (b0 == b1 && pos0 + 1 < CAP) {
        u32x4 qq = {q0.x, q0.y, q1.x, q1.y};
        *reinterpret_cast<u32x4*>(&P1[(size_t)b0 * CAP + pos0]) = qq;
      } else {
        if (pos0 < CAP) P1[(size_t)b0 * CAP + pos0] = q0;
        unsigned pos1 = alloc[b1] + (j2 + 1 - sbase[b1]);
        if (pos1 < CAP) P1[(size_t)b1 * CAP + pos1] = q1;
      }
    }
    __syncthreads();
  }
}

// ---- K2: merged accumulate. Pairs in regs (no spill), 4 x 128 KB sweeps ----
__global__ __launch_bounds__(512, 2) void k_waccum(const u32x2* __restrict__ P1,
                                                   const unsigned* __restrict__ gcur,
                                                   float* __restrict__ out) {
  __shared__ float w[WFL];   // 128 KB
  const int c = blockIdx.x;
  const unsigned len = min(gcur[c], (unsigned)CAP);
  const u32x2* P = P1 + (size_t)c * CAP;
  const u32x4* P4 = reinterpret_cast<const u32x4*>(P);  // c*CAP*8 is 16B-aligned
  u32x2 p[KREG];             // 144 VGPRs @ 512 thr (256-VGPR budget) - no spill
  #pragma unroll
  for (int k = 0; k < KREG / 2; ++k) {   // 36 x 16 B loads (2 pairs each)
    unsigned j = (unsigned)(k * 512) + threadIdx.x;   // vec2 index
    u32x4 q = __builtin_nontemporal_load(P4 + j);     // may read stale past len
    unsigned j2 = 2u * j;
    p[2 * k]     = (j2     < len) ? (u32x2){q.x, q.y} : (u32x2){0u, 0xFFFFFFFFu};
    p[2 * k + 1] = (j2 + 1 < len) ? (u32x2){q.z, q.w} : (u32x2){0u, 0xFFFFFFFFu};
  }
  f32x4* w4 = reinterpret_cast<f32x4*>(w);
  for (int sub = 0; sub < NSUB; ++sub) {
    const unsigned key = ((unsigned)c << 2) | (unsigned)sub;  // idx>>SSH value
    for (int i = threadIdx.x; i < WFL / 4; i += 512) w4[i] = (f32x4){0.f, 0.f, 0.f, 0.f};
    __syncthreads();
    #pragma unroll
    for (int k = 0; k < KREG; ++k) {
      if ((p[k].y >> SSH) == key)   // sentinel 0xFFFFFFFF matches no key
        atomicAdd(&w[p[k].y & (WFL - 1)], __uint_as_float(p[k].x));  // ds_add_f32
    }
    __syncthreads();
    f32x4* o = reinterpret_cast<f32x4*>(out + ((size_t)c << CSH) + ((size_t)sub << SSH));
    for (int i = threadIdx.x; i < WFL / 4; i += 512)
      __builtin_nontemporal_store(w4[i], o + i);
    __syncthreads();
  }
}

// ---- Fallback: plain atomic scatter (measured ~1.77 ms) ----
__global__ __launch_bounds__(256) void unpool_scatter_kernel(
    const float* __restrict__ x, const int* __restrict__ ind,
    float* __restrict__ out, int n4) {
  int i = blockIdx.x * blockDim.x + threadIdx.x;
  if (i >= n4) return;
  f32x4 v  = reinterpret_cast<const f32x4*>(x)[i];
  i32x4 id = reinterpret_cast<const i32x4*>(ind)[i];
  unsafeAtomicAdd(&out[id.x], v.x);
  unsafeAtomicAdd(&out[id.y], v.y);
  unsafeAtomicAdd(&out[id.z], v.z);
  unsafeAtomicAdd(&out[id.w], v.w);
}

extern "C" void kernel_launch(void* const* d_in, const int* in_sizes, int n_in,
                              void* d_out, int out_size, void* d_ws, size_t ws_size,
                              hipStream_t stream) {
  const float* x   = (const float*)d_in[0];
  const int*   ind = (const int*)d_in[1];
  float*       out = (float*)d_out;
  const int n = in_sizes[0];

  // ws layout: gcur[1024] | P1 (1024 x CAP x 8 B = 302 MB)
  const size_t szG  = ((size_t)NB1 * sizeof(unsigned) + 255) & ~(size_t)255;
  const size_t szP1 = (size_t)NB1 * CAP * sizeof(u32x2);
  const size_t need = szG + szP1;

  const bool shape_ok = (n == N_TOT) && (out_size == OUT_TOT);

  if (!shape_ok || ws_size < need) {
    (void)hipMemsetAsync(d_out, 0, (size_t)out_size * sizeof(float), stream);
    const int n4 = n / 4;
    unpool_scatter_kernel<<<(n4 + 255) / 256, 256, 0, stream>>>(x, ind, out, n4);
    return;
  }

  char* ws = (char*)d_ws;
  unsigned* gcur = (unsigned*)ws;
  u32x2*    P1   = (u32x2*)(ws + szG);

  (void)hipMemsetAsync(gcur, 0, (size_t)NB1 * sizeof(unsigned), stream);
  k_scatter<<<T1,  1024, 0, stream>>>(x, ind, gcur, P1);
  k_waccum <<<NB1,  512, 0, stream>>>(P1, gcur, out);
  // Output fully covered by dense windows -> no memset of d_out needed.
}

// Round 15
// 367.872 us; speedup vs baseline: 1.1521x; 1.0397x over previous
//
#include <hip/hip_runtime.h>

// Max-unpooling scatter-add, hist-free radix (1024 buckets): LDS batch-sort
// + global atomic cursor allocation into fixed-capacity bucket regions, then
// merged accumulate with pairs held in registers (512 thr x 72 pairs = 144
// VGPR, no spill), 4 x 128 KB LDS sweeps.
//   out = zeros(total); out[ind[i]] += x[i]
// N = 2^25 pairs, OUT = 2^27 floats (536.9 MB).
//
// R15 = R12 (best, 379 us) + waccum fixes:
//  (1) conditional P1 loads: stop at len, not CAP (-12% = -34 MB FETCH)
//  (2) fused writeout+zero: one LDS pass + one barrier fewer per sweep
//      (12 -> 8 barrier-drains per block)
//  (3) initial zero overlapped with in-flight global loads.
// (R13 L3-compression and R14 paired stores both refuted; scatter measured
// ~97 us at 5.8 TB/s in R11 -> near-optimal, left as R12.)

typedef float    f32x4 __attribute__((ext_vector_type(4)));
typedef int      i32x4 __attribute__((ext_vector_type(4)));
typedef unsigned u32x2 __attribute__((ext_vector_type(2)));
typedef unsigned u32x4 __attribute__((ext_vector_type(4)));

#define N_TOT   (1 << 25)     // input pairs
#define OUT_TOT (1 << 27)     // output floats
#define T1      1024          // scatter tiles
#define PT      (N_TOT / T1)  // 32768 pairs/tile
#define PT4     (PT / 4)      // 8192 vec4/tile
#define NB1     1024          // buckets
#define CSH     17            // bucket = idx >> 17 (window 2^17 floats = 512 KB)
#define CAP     36864         // per-bucket capacity (mean 32768 + 22 sigma), even
#define SSH     15            // sweep = (idx >> 15) & 3
#define NSUB    4
#define WFL     32768         // floats per sweep window (128 KB LDS)
#define BATCH   16384         // pairs per sort batch (128 KB LDS sbuf)
#define KREG    72            // pairs/thread in k_waccum (512 thr: CAP exactly)

// ---- K1: scatter with LDS batch-sort + atomic segment allocation ----
__global__ __launch_bounds__(1024) void k_scatter(const float* __restrict__ x,
                                                  const int* __restrict__ ind,
                                                  unsigned* __restrict__ gcur,
                                                  u32x2* __restrict__ P1) {
  __shared__ u32x2    sbuf[BATCH];                        // 128 KB
  __shared__ unsigned hist[NB1], sbase[NB1], alloc[NB1];  // 12 KB
  const int t = blockIdx.x;
  const i32x4* pi = reinterpret_cast<const i32x4*>(ind) + (size_t)t * PT4;
  const f32x4* pv = reinterpret_cast<const f32x4*>(x)  + (size_t)t * PT4;

  for (int bt = 0; bt < 2; ++bt) {
    const int v0 = bt * (BATCH / 4);
    i32x4 idx[4];
    f32x4 val[4];
    #pragma unroll
    for (int q = 0; q < 4; ++q) {
      idx[q] = __builtin_nontemporal_load(pi + v0 + q * 1024 + threadIdx.x);
      val[q] = __builtin_nontemporal_load(pv + v0 + q * 1024 + threadIdx.x);
    }
    hist[threadIdx.x] = 0;
    __syncthreads();
    unsigned r[16];
    #pragma unroll
    for (int q = 0; q < 4; ++q) {
      r[4 * q + 0] = atomicAdd(&hist[(unsigned)idx[q].x >> CSH], 1u);
      r[4 * q + 1] = atomicAdd(&hist[(unsigned)idx[q].y >> CSH], 1u);
      r[4 * q + 2] = atomicAdd(&hist[(unsigned)idx[q].z >> CSH], 1u);
      r[4 * q + 3] = atomicAdd(&hist[(unsigned)idx[q].w >> CSH], 1u);
    }
    __syncthreads();
    // Allocate this batch's per-bucket segments: 1 global atomic/bucket on
    // 1024 hot (L2-resident) addresses. Latency hides under the scan.
    alloc[threadIdx.x] = atomicAdd(&gcur[threadIdx.x], hist[threadIdx.x]);
    if (threadIdx.x < 64) {   // exclusive scan of hist[1024]: 16 entries/lane
      const unsigned lane = threadIdx.x;
      unsigned h[16], sum = 0;
      #pragma unroll
      for (int j = 0; j < 16; ++j) { h[j] = hist[16 * lane + j]; sum += h[j]; }
      unsigned inc = sum;
      for (int off = 1; off < 64; off <<= 1) {
        unsigned o = __shfl_up(inc, off, 64);
        if (lane >= (unsigned)off) inc += o;
      }
      unsigned exc = inc - sum;
      #pragma unroll
      for (int j = 0; j < 16; ++j) { sbase[16 * lane + j] = exc; exc += h[j]; }
    }
    __syncthreads();
    #pragma unroll
    for (int q = 0; q < 4; ++q) {
      sbuf[sbase[(unsigned)idx[q].x >> CSH] + r[4 * q + 0]] =
          (u32x2){__float_as_uint(val[q].x), (unsigned)idx[q].x};
      sbuf[sbase[(unsigned)idx[q].y >> CSH] + r[4 * q + 1]] =
          (u32x2){__float_as_uint(val[q].y), (unsigned)idx[q].y};
      sbuf[sbase[(unsigned)idx[q].z >> CSH] + r[4 * q + 2]] =
          (u32x2){__float_as_uint(val[q].z), (unsigned)idx[q].z};
      sbuf[sbase[(unsigned)idx[q].w >> CSH] + r[4 * q + 3]] =
          (u32x2){__float_as_uint(val[q].w), (unsigned)idx[q].w};
    }
    __syncthreads();
    #pragma unroll
    for (int k = 0; k < BATCH / 1024; ++k) {   // 16 coalesced segment stores
      unsigned j = (unsigned)(k * 1024 + threadIdx.x);
      u32x2 q = sbuf[j];
      unsigned b = q.y >> CSH;
      unsigned pos = alloc[b] + (j - sbase[b]);
      if (pos < CAP)   // statistically impossible overflow; guard OOB anyway
        P1[(size_t)b * CAP + pos] = q;
    }
    __syncthreads();
  }
}

// ---- K2: merged accumulate. Pairs in regs (no spill), 4 x 128 KB sweeps ----
__global__ __launch_bounds__(512, 2) void k_waccum(const u32x2* __restrict__ P1,
                                                   const unsigned* __restrict__ gcur,
                                                   float* __restrict__ out) {
  __shared__ float w[WFL];   // 128 KB
  const int c = blockIdx.x;
  const unsigned len = min(gcur[c], (unsigned)CAP);
  const u32x4* P4 = reinterpret_cast<const u32x4*>(P1 + (size_t)c * CAP);
  u32x2 p[KREG];             // 144 VGPRs @ 512 thr (256-VGPR budget) - no spill
  #pragma unroll
  for (int k = 0; k < KREG / 2; ++k) {   // <=36 x 16 B loads (2 pairs each)
    unsigned j = (unsigned)(k * 512) + threadIdx.x;   // vec2 index
    unsigned j2 = 2u * j;
    if (j2 + 1 < len) {
      u32x4 q = __builtin_nontemporal_load(P4 + j);
      p[2 * k]     = (u32x2){q.x, q.y};
      p[2 * k + 1] = (u32x2){q.z, q.w};
    } else if (j2 < len) {
      u32x2 q = __builtin_nontemporal_load(
                  reinterpret_cast<const u32x2*>(P4) + j2);
      p[2 * k]     = q;
      p[2 * k + 1] = (u32x2){0u, 0xFFFFFFFFu};
    } else {
      p[2 * k]     = (u32x2){0u, 0xFFFFFFFFu};   // sentinel: matches no key
      p[2 * k + 1] = (u32x2){0u, 0xFFFFFFFFu};
    }
  }
  // Initial zero of w: issued after the loads, so it overlaps their latency.
  f32x4* w4 = reinterpret_cast<f32x4*>(w);
  for (int i = threadIdx.x; i < WFL / 4; i += 512)
    w4[i] = (f32x4){0.f, 0.f, 0.f, 0.f};
  __syncthreads();
  for (int sub = 0; sub < NSUB; ++sub) {
    const unsigned key = ((unsigned)c << 2) | (unsigned)sub;  // idx>>SSH value
    #pragma unroll
    for (int k = 0; k < KREG; ++k) {
      if ((p[k].y >> SSH) == key)
        atomicAdd(&w[p[k].y & (WFL - 1)], __uint_as_float(p[k].x));  // ds_add_f32
    }
    __syncthreads();
    f32x4* o = reinterpret_cast<f32x4*>(out + ((size_t)c << CSH) + ((size_t)sub << SSH));
    if (sub + 1 < NSUB) {
      // Fused writeout + re-zero: one LDS pass instead of two, one barrier
      // per sweep instead of two.
      for (int i = threadIdx.x; i < WFL / 4; i += 512) {
        f32x4 q = w4[i];
        __builtin_nontemporal_store(q, o + i);
        w4[i] = (f32x4){0.f, 0.f, 0.f, 0.f};
      }
    } else {
      for (int i = threadIdx.x; i < WFL / 4; i += 512)
        __builtin_nontemporal_store(w4[i], o + i);
    }
    __syncthreads();
  }
}

// ---- Fallback: plain atomic scatter (measured ~1.77 ms) ----
__global__ __launch_bounds__(256) void unpool_scatter_kernel(
    const float* __restrict__ x, const int* __restrict__ ind,
    float* __restrict__ out, int n4) {
  int i = blockIdx.x * blockDim.x + threadIdx.x;
  if (i >= n4) return;
  f32x4 v  = reinterpret_cast<const f32x4*>(x)[i];
  i32x4 id = reinterpret_cast<const i32x4*>(ind)[i];
  unsafeAtomicAdd(&out[id.x], v.x);
  unsafeAtomicAdd(&out[id.y], v.y);
  unsafeAtomicAdd(&out[id.z], v.z);
  unsafeAtomicAdd(&out[id.w], v.w);
}

extern "C" void kernel_launch(void* const* d_in, const int* in_sizes, int n_in,
                              void* d_out, int out_size, void* d_ws, size_t ws_size,
                              hipStream_t stream) {
  const float* x   = (const float*)d_in[0];
  const int*   ind = (const int*)d_in[1];
  float*       out = (float*)d_out;
  const int n = in_sizes[0];

  // ws layout: gcur[1024] | P1 (1024 x CAP x 8 B = 302 MB)
  const size_t szG  = ((size_t)NB1 * sizeof(unsigned) + 255) & ~(size_t)255;
  const size_t szP1 = (size_t)NB1 * CAP * sizeof(u32x2);
  const size_t need = szG + szP1;

  const bool shape_ok = (n == N_TOT) && (out_size == OUT_TOT);

  if (!shape_ok || ws_size < need) {
    (void)hipMemsetAsync(d_out, 0, (size_t)out_size * sizeof(float), stream);
    const int n4 = n / 4;
    unpool_scatter_kernel<<<(n4 + 255) / 256, 256, 0, stream>>>(x, ind, out, n4);
    return;
  }

  char* ws = (char*)d_ws;
  unsigned* gcur = (unsigned*)ws;
  u32x2*    P1   = (u32x2*)(ws + szG);

  (void)hipMemsetAsync(gcur, 0, (size_t)NB1 * sizeof(unsigned), stream);
  k_scatter<<<T1,  1024, 0, stream>>>(x, ind, gcur, P1);
  k_waccum <<<NB1,  512, 0, stream>>>(P1, gcur, out);
  // Output fully covered by dense windows -> no memset of d_out needed.
}